// Round 1
// baseline (86.211 us; speedup 1.0000x reference)
//
#include <hip/hip_runtime.h>

#define BATCH 16
#define PDEG  3          // P == Q == 3
#define MAXSPAN 127      // M == N == 127
#define KLEN  132        // knots per batch: M + P + 2
#define NSAMP 256        // SU == SV
#define NSPANS 126       // KLEN - 2*PDEG
#define GRID_PTS 128     // M+1 == N+1

// Scratch in device globals: fully overwritten by basis_kernel before
// eval_kernel reads them on every call (stream-ordered), so re-poisoning of
// d_ws is irrelevant and no ws_size assumption is needed.
__device__ float g_N[2][BATCH][NSAMP][4];   // [axis(u=0,v=1)][b][sample][r]
__device__ int   g_span[2][BATCH][NSAMP];

// One block per batch; 256 threads, one per sample. Knot pipeline in double:
// clamp -> cumsum -> normalize -> span search -> Cox-de Boor (deg 3),
// faithful to the reference including the where() fallbacks.
__global__ void basis_kernel(const float* __restrict__ knots,
                             const float* __restrict__ t_arr,
                             int axis, int max_span)
{
    __shared__ double s_w[KLEN];    // clamped raw knots, then unused
    __shared__ double s_kn[KLEN];   // normalized knots
    const int b   = blockIdx.x;
    const int tid = threadIdx.x;

    if (tid < KLEN) {
        float w = knots[b * KLEN + tid];
        s_w[tid] = (w < 0.0f) ? 1.0e-4 : (double)w;
    }
    __syncthreads();

    if (tid == 0) {
        double run = 0.0;
        for (int j = 0; j < KLEN; ++j) { run += s_w[j]; s_kn[j] = run; }
    }
    __syncthreads();

    const double k0  = s_kn[0];
    const double inv = 1.0 / (s_kn[KLEN - 1] - k0);
    double mykn = 0.0;
    if (tid < KLEN) mykn = (s_kn[tid] - k0) * inv;
    __syncthreads();
    if (tid < KLEN) s_kn[tid] = mykn;
    __syncthreads();

    const double t = (double)t_arr[tid];

    // span: first-argmin over masked = (d > EPS ? d : 1.0), d = t - K[j+deg]
    double best = 1.0e300;
    int jmin = 0;
    for (int j = 0; j < NSPANS; ++j) {
        double d = t - s_kn[j + PDEG];
        double m = (d > 1.0e-8) ? d : 1.0;
        if (m < best) { best = m; jmin = j; }   // strict <: keeps first min
    }
    int span = jmin + PDEG;
    if (span > max_span) span = max_span;       // lower clip redundant (>=3)

    // Cox-de Boor, degree 3, exact reference recurrence
    double Ni[PDEG + 1];
    Ni[0] = 1.0;
    for (int k = 1; k <= PDEG; ++k) {
        double saved = 0.0;
        for (int r = 0; r < k; ++r) {
            double K1 = s_kn[span + r + 1];
            double K2 = s_kn[span + 1 - k + r];
            double denom = (K1 - t) + (t - K2);
            double temp = (denom == 0.0) ? 1.0e-4 : (Ni[r] / denom);
            Ni[r] = saved + (K1 - t) * temp;
            saved = (t - K2) * temp;
        }
        Ni[k] = saved;
    }

#pragma unroll
    for (int r = 0; r < 4; ++r)
        g_N[axis][b][tid][r] = (float)Ni[r];
    g_span[axis][b][tid] = span;
}

// One thread per (b, su, sv): 4x4 weighted gather of control points.
__global__ void eval_kernel(const float* __restrict__ ctrl,
                            float* __restrict__ out)
{
    const int sv = threadIdx.x;
    const int su = blockIdx.x;
    const int b  = blockIdx.y;

    const int us = g_span[0][b][su];
    const int vs = g_span[1][b][sv];
    const float4 nu4 = *(const float4*)&g_N[0][b][su][0];
    const float4 nv4 = *(const float4*)&g_N[1][b][sv][0];
    const float nu[4] = {nu4.x, nu4.y, nu4.z, nu4.w};
    const float nv[4] = {nv4.x, nv4.y, nv4.z, nv4.w};

    const float* __restrict__ base =
        ctrl + (size_t)b * GRID_PTS * GRID_PTS * 3;

    float acc0 = 0.f, acc1 = 0.f, acc2 = 0.f;
#pragma unroll
    for (int p = 0; p < 4; ++p) {
        const float* __restrict__ row =
            base + ((size_t)(us - PDEG + p) * GRID_PTS + (vs - PDEG)) * 3;
        const float wu = nu[p];
#pragma unroll
        for (int q = 0; q < 4; ++q) {
            const float w = wu * nv[q];
            acc0 += w * row[q * 3 + 0];
            acc1 += w * row[q * 3 + 1];
            acc2 += w * row[q * 3 + 2];
        }
    }

    const size_t o = (((size_t)b * NSAMP + su) * NSAMP + sv) * 3;
    out[o + 0] = acc0;
    out[o + 1] = acc1;
    out[o + 2] = acc2;
}

extern "C" void kernel_launch(void* const* d_in, const int* in_sizes, int n_in,
                              void* d_out, int out_size, void* d_ws, size_t ws_size,
                              hipStream_t stream) {
    const float* ctrl   = (const float*)d_in[0];  // (16,128,128,3)
    const float* knot_u = (const float*)d_in[1];  // (16,132)
    const float* knot_v = (const float*)d_in[2];  // (16,132)
    const float* u      = (const float*)d_in[3];  // (256,)
    const float* v      = (const float*)d_in[4];  // (256,)
    float* out = (float*)d_out;                   // (16,256,256,3)

    basis_kernel<<<BATCH, NSAMP, 0, stream>>>(knot_u, u, 0, MAXSPAN);
    basis_kernel<<<BATCH, NSAMP, 0, stream>>>(knot_v, v, 1, MAXSPAN);

    dim3 grid(NSAMP, BATCH);
    eval_kernel<<<grid, NSAMP, 0, stream>>>(ctrl, out);
}

// Round 2
// 76.274 us; speedup vs baseline: 1.1303x; 1.1303x over previous
//
#include <hip/hip_runtime.h>

#define BATCH 16
#define PDEG  3          // P == Q == 3
#define MAXSPAN 127      // M == N == 127
#define KLEN  132        // knots per batch: M + P + 2
#define NSAMP 256        // SU == SV
#define NSPANS 126       // KLEN - 2*PDEG
#define GRID_PTS 128     // M+1 == N+1
#define ROWF (GRID_PTS * 3)   // floats per control row = 384

// Scratch in device globals: fully overwritten by basis_kernel before
// eval_kernel reads them (stream-ordered), so harness re-poison of d_ws is
// irrelevant and no ws_size assumption is needed.
__device__ float g_N[2][BATCH][NSAMP][4];   // [axis(u=0,v=1)][b][sample][r]
__device__ int   g_span[2][BATCH][NSAMP];

// grid = (BATCH, 2): blockIdx.y selects axis (0=u, 1=v). 256 threads.
// Knot pipeline in f64: clamp -> parallel scan -> normalize -> span search ->
// Cox-de Boor degree 3, faithful to the reference where() fallbacks.
__global__ void basis_kernel(const float* __restrict__ knot_u,
                             const float* __restrict__ knot_v,
                             const float* __restrict__ u_arr,
                             const float* __restrict__ v_arr)
{
    __shared__ double s_kn[KLEN];
    const int b    = blockIdx.x;
    const int axis = blockIdx.y;
    const int tid  = threadIdx.x;

    const float* __restrict__ knots = axis ? knot_v : knot_u;
    const float* __restrict__ t_arr = axis ? v_arr  : u_arr;

    if (tid < KLEN) {
        float w = knots[b * KLEN + tid];
        s_kn[tid] = (w < 0.0f) ? 1.0e-4 : (double)w;
    }
    __syncthreads();

    // Hillis-Steele inclusive scan over 132 elements (8 steps)
    for (int off = 1; off < KLEN; off <<= 1) {
        double add = 0.0;
        if (tid < KLEN && tid >= off) add = s_kn[tid - off];
        __syncthreads();
        if (tid < KLEN) s_kn[tid] += add;
        __syncthreads();
    }

    const double k0  = s_kn[0];
    const double inv = 1.0 / (s_kn[KLEN - 1] - k0);
    double mykn = 0.0;
    if (tid < KLEN) mykn = (s_kn[tid] - k0) * inv;
    __syncthreads();
    if (tid < KLEN) s_kn[tid] = mykn;
    __syncthreads();

    const double t = (double)t_arr[tid];

    // span: first-argmin over masked = (d > EPS ? d : 1.0), d = t - K[j+deg]
    double best = 1.0e300;
    int jmin = 0;
    for (int j = 0; j < NSPANS; ++j) {
        double d = t - s_kn[j + PDEG];
        double m = (d > 1.0e-8) ? d : 1.0;
        if (m < best) { best = m; jmin = j; }   // strict <: keeps first min
    }
    int span = jmin + PDEG;
    if (span > MAXSPAN) span = MAXSPAN;         // lower clip redundant (>=3)

    // Cox-de Boor, degree 3, exact reference recurrence
    double Ni[PDEG + 1];
    Ni[0] = 1.0;
    for (int k = 1; k <= PDEG; ++k) {
        double saved = 0.0;
        for (int r = 0; r < k; ++r) {
            double K1 = s_kn[span + r + 1];
            double K2 = s_kn[span + 1 - k + r];
            double denom = (K1 - t) + (t - K2);
            double temp = (denom == 0.0) ? 1.0e-4 : (Ni[r] / denom);
            Ni[r] = saved + (K1 - t) * temp;
            saved = (t - K2) * temp;
        }
        Ni[k] = saved;
    }

#pragma unroll
    for (int r = 0; r < 4; ++r)
        g_N[axis][b][tid][r] = (float)Ni[r];
    g_span[axis][b][tid] = span;
}

// Block = (su, b), thread = sv. The 4 control rows needed by the whole block
// (us-3 .. us) are one contiguous 6 KB chunk -> coalesced float4 staging into
// LDS, then a 4x4x3 contraction from LDS.
__global__ void __launch_bounds__(256)
eval_kernel(const float* __restrict__ ctrl, float* __restrict__ out)
{
    __shared__ float s_rows[4 * ROWF];          // 6 KB
    const int sv = threadIdx.x;
    const int su = blockIdx.x;
    const int b  = blockIdx.y;

    const int us = g_span[0][b][su];            // uniform across block

    // stage 1536 contiguous floats = 384 float4 (base is 1536B-aligned)
    const float4* __restrict__ src = (const float4*)
        (ctrl + ((size_t)b * GRID_PTS + (size_t)(us - PDEG)) * ROWF);
    float4* dst = (float4*)s_rows;
    dst[sv] = src[sv];
    if (sv < 128) dst[256 + sv] = src[256 + sv];

    const int vs = g_span[1][b][sv];
    const float4 nu4 = *(const float4*)&g_N[0][b][su][0];
    const float4 nv4 = *(const float4*)&g_N[1][b][sv][0];
    const float nu[4] = {nu4.x, nu4.y, nu4.z, nu4.w};
    const float nv[4] = {nv4.x, nv4.y, nv4.z, nv4.w};

    __syncthreads();

    const int c = (vs - PDEG) * 3;              // column offset in floats
    float acc0 = 0.f, acc1 = 0.f, acc2 = 0.f;
#pragma unroll
    for (int p = 0; p < 4; ++p) {
        const float* rp = s_rows + p * ROWF + c;
        const float wu = nu[p];
#pragma unroll
        for (int q = 0; q < 4; ++q) {
            const float w = wu * nv[q];
            acc0 += w * rp[q * 3 + 0];
            acc1 += w * rp[q * 3 + 1];
            acc2 += w * rp[q * 3 + 2];
        }
    }

    const size_t o = (((size_t)b * NSAMP + su) * NSAMP + sv) * 3;
    out[o + 0] = acc0;
    out[o + 1] = acc1;
    out[o + 2] = acc2;
}

extern "C" void kernel_launch(void* const* d_in, const int* in_sizes, int n_in,
                              void* d_out, int out_size, void* d_ws, size_t ws_size,
                              hipStream_t stream) {
    const float* ctrl   = (const float*)d_in[0];  // (16,128,128,3)
    const float* knot_u = (const float*)d_in[1];  // (16,132)
    const float* knot_v = (const float*)d_in[2];  // (16,132)
    const float* u      = (const float*)d_in[3];  // (256,)
    const float* v      = (const float*)d_in[4];  // (256,)
    float* out = (float*)d_out;                   // (16,256,256,3)

    dim3 bgrid(BATCH, 2);
    basis_kernel<<<bgrid, NSAMP, 0, stream>>>(knot_u, knot_v, u, v);

    dim3 egrid(NSAMP, BATCH);
    eval_kernel<<<egrid, NSAMP, 0, stream>>>(ctrl, out);
}

// Round 3
// 76.128 us; speedup vs baseline: 1.1324x; 1.0019x over previous
//
#include <hip/hip_runtime.h>

#define BATCH 16
#define PDEG  3          // P == Q == 3
#define MAXSPAN 127      // M == N == 127
#define KLEN  132        // knots per batch: M + P + 2
#define NSAMP 256        // SU == SV
#define NSPANS 126       // KLEN - 2*PDEG
#define GRID_PTS 128     // M+1 == N+1
#define ROWF (GRID_PTS * 3)   // floats per control row = 384

// Scratch in device globals: fully overwritten by basis_kernel before
// eval_kernel reads them (stream-ordered), so harness re-poison of d_ws is
// irrelevant and no ws_size assumption is needed.
__device__ float g_N[2][BATCH][NSAMP][4];   // [axis(u=0,v=1)][b][sample][r]
__device__ int   g_span[2][BATCH][NSAMP];

// grid = (BATCH, 2): blockIdx.y selects axis (0=u, 1=v). 256 threads.
// Knot pipeline in f64: clamp -> parallel scan -> normalize -> span search ->
// Cox-de Boor degree 3, faithful to the reference where() fallbacks.
__global__ void basis_kernel(const float* __restrict__ knot_u,
                             const float* __restrict__ knot_v,
                             const float* __restrict__ u_arr,
                             const float* __restrict__ v_arr)
{
    __shared__ double s_kn[KLEN];
    const int b    = blockIdx.x;
    const int axis = blockIdx.y;
    const int tid  = threadIdx.x;

    const float* __restrict__ knots = axis ? knot_v : knot_u;
    const float* __restrict__ t_arr = axis ? v_arr  : u_arr;

    if (tid < KLEN) {
        float w = knots[b * KLEN + tid];
        s_kn[tid] = (w < 0.0f) ? 1.0e-4 : (double)w;
    }
    __syncthreads();

    // Hillis-Steele inclusive scan over 132 elements (8 steps)
    for (int off = 1; off < KLEN; off <<= 1) {
        double add = 0.0;
        if (tid < KLEN && tid >= off) add = s_kn[tid - off];
        __syncthreads();
        if (tid < KLEN) s_kn[tid] += add;
        __syncthreads();
    }

    const double k0  = s_kn[0];
    const double inv = 1.0 / (s_kn[KLEN - 1] - k0);
    double mykn = 0.0;
    if (tid < KLEN) mykn = (s_kn[tid] - k0) * inv;
    __syncthreads();
    if (tid < KLEN) s_kn[tid] = mykn;
    __syncthreads();

    const double t = (double)t_arr[tid];

    // span: first-argmin over masked = (d > EPS ? d : 1.0), d = t - K[j+deg]
    // linear scan: independent loads pipeline well; faithful tie semantics
    double best = 1.0e300;
    int jmin = 0;
    for (int j = 0; j < NSPANS; ++j) {
        double d = t - s_kn[j + PDEG];
        double m = (d > 1.0e-8) ? d : 1.0;
        if (m < best) { best = m; jmin = j; }   // strict <: keeps first min
    }
    int span = jmin + PDEG;
    if (span > MAXSPAN) span = MAXSPAN;         // lower clip redundant (>=3)

    // Cox-de Boor, degree 3, exact reference recurrence
    double Ni[PDEG + 1];
    Ni[0] = 1.0;
    for (int k = 1; k <= PDEG; ++k) {
        double saved = 0.0;
        for (int r = 0; r < k; ++r) {
            double K1 = s_kn[span + r + 1];
            double K2 = s_kn[span + 1 - k + r];
            double denom = (K1 - t) + (t - K2);
            double temp = (denom == 0.0) ? 1.0e-4 : (Ni[r] / denom);
            Ni[r] = saved + (K1 - t) * temp;
            saved = (t - K2) * temp;
        }
        Ni[k] = saved;
    }

#pragma unroll
    for (int r = 0; r < 4; ++r)
        g_N[axis][b][tid][r] = (float)Ni[r];
    g_span[axis][b][tid] = span;
}

// Block = (su, b), thread = sv. Separable contraction:
//   phase 0: stage rows us-3..us (one contiguous 6 KB chunk) into LDS
//   phase 1: tmp[j] = sum_p nu[p] * row_p[j]   (96 threads x float4)
//   phase 2: out_d  = sum_q nv[q] * tmp[(vs-3)*3 + 3q + d]
__global__ void __launch_bounds__(256)
eval_kernel(const float* __restrict__ ctrl, float* __restrict__ out)
{
    __shared__ float s_rows[4 * ROWF];          // 6 KB
    __shared__ float s_tmp[ROWF];               // 1.5 KB
    const int sv = threadIdx.x;
    const int su = blockIdx.x;
    const int b  = blockIdx.y;

    const int us = g_span[0][b][su];            // uniform across block
    const float4 nu4 = *(const float4*)&g_N[0][b][su][0];   // uniform

    // stage 1536 contiguous floats = 384 float4 (base is 1536B-aligned)
    const float4* __restrict__ src = (const float4*)
        (ctrl + ((size_t)b * GRID_PTS + (size_t)(us - PDEG)) * ROWF);
    float4* dst = (float4*)s_rows;
    dst[sv] = src[sv];
    if (sv < 128) dst[256 + sv] = src[256 + sv];

    const int vs = g_span[1][b][sv];
    const float4 nv4 = *(const float4*)&g_N[1][b][sv][0];
    const float nv[4] = {nv4.x, nv4.y, nv4.z, nv4.w};

    __syncthreads();

    // phase 1: 384 floats = 96 float4 column-groups; threads 0..95
    if (sv < ROWF / 4) {
        const float4* r4 = (const float4*)s_rows;
        float4 a0 = r4[0 * 96 + sv];
        float4 a1 = r4[1 * 96 + sv];
        float4 a2 = r4[2 * 96 + sv];
        float4 a3 = r4[3 * 96 + sv];
        float4 t4;
        t4.x = nu4.x * a0.x + nu4.y * a1.x + nu4.z * a2.x + nu4.w * a3.x;
        t4.y = nu4.x * a0.y + nu4.y * a1.y + nu4.z * a2.y + nu4.w * a3.y;
        t4.z = nu4.x * a0.z + nu4.y * a1.z + nu4.z * a2.z + nu4.w * a3.z;
        t4.w = nu4.x * a0.w + nu4.y * a1.w + nu4.z * a2.w + nu4.w * a3.w;
        ((float4*)s_tmp)[sv] = t4;
    }

    __syncthreads();

    // phase 2: contract over q
    const float* tp = s_tmp + (vs - PDEG) * 3;
    float acc0 = 0.f, acc1 = 0.f, acc2 = 0.f;
#pragma unroll
    for (int q = 0; q < 4; ++q) {
        const float w = nv[q];
        acc0 += w * tp[q * 3 + 0];
        acc1 += w * tp[q * 3 + 1];
        acc2 += w * tp[q * 3 + 2];
    }

    const size_t o = (((size_t)b * NSAMP + su) * NSAMP + sv) * 3;
    out[o + 0] = acc0;
    out[o + 1] = acc1;
    out[o + 2] = acc2;
}

extern "C" void kernel_launch(void* const* d_in, const int* in_sizes, int n_in,
                              void* d_out, int out_size, void* d_ws, size_t ws_size,
                              hipStream_t stream) {
    const float* ctrl   = (const float*)d_in[0];  // (16,128,128,3)
    const float* knot_u = (const float*)d_in[1];  // (16,132)
    const float* knot_v = (const float*)d_in[2];  // (16,132)
    const float* u      = (const float*)d_in[3];  // (256,)
    const float* v      = (const float*)d_in[4];  // (256,)
    float* out = (float*)d_out;                   // (16,256,256,3)

    dim3 bgrid(BATCH, 2);
    basis_kernel<<<bgrid, NSAMP, 0, stream>>>(knot_u, knot_v, u, v);

    dim3 egrid(NSAMP, BATCH);
    eval_kernel<<<egrid, NSAMP, 0, stream>>>(ctrl, out);
}